// Round 7
// baseline (140.473 us; speedup 1.0000x reference)
//
#include <hip/hip_runtime.h>
#include <stdint.h>

typedef float f32x16 __attribute__((ext_vector_type(16)));
typedef int v8i __attribute__((ext_vector_type(8)));
typedef int v4i __attribute__((ext_vector_type(4)));

#define BDIM 8192

// fp8 matrices stored 16B-run k-major for the K=64 scaled MFMA:
//   for byte (row, k): S = k>>6 (MFMA step), h = (k>>5)&1 (lane k-half),
//   q = (k>>4)&1 (16B half of the 32B run):
//   addr = S*524288 + h*262144 + q*131072 + row*16 + (k&15)     (1 MB per matrix)
// Segment index s = S*4 + h*2 + q (8 segments per matrix). v8i = (q0 16B,
// q1 16B) reproduces the 32B k-run byte order. Scales uniform 1.0 (0x7F).
//
// REGISTER KNIFE-EDGE (r3/r4): per-wave body = 64 AGPR acc + ~56 VGPR.
// Any multi-tile-per-block LOOP tips into scratch (r3: 451 MB spill
// writes; r4: 97 MB). Scaling up must add WAVES, not per-wave tiles.
//
// GRID-RENDEZVOUS IS DEAD (r1/r6): release/acquire at agent scope = L2
// flush storm (+47us); even relaxed returning RMWs on one counter
// serialize 4096 blocks at the coherence point (+30us). 3-kernel form.

// fp32 [8192,128] -> fp8 e4m3 (16B-run layout) + fp32 row sum-of-squares.
__global__ __launch_bounds__(256) void prep_kernel(const float* __restrict__ out_f,
                                                   const float* __restrict__ tgt_f,
                                                   uint8_t* __restrict__ ak,
                                                   float* __restrict__ xxyy) {
    const float* src = blockIdx.y ? tgt_f : out_f;
    uint8_t* dst = ak + (size_t)blockIdx.y * (1u << 20);
    float* nrm = xxyy + (size_t)blockIdx.y * BDIM;

    const int tid = threadIdx.x;
    const int lane = tid & 63;
    const int w = tid >> 6;
    const int jg = lane & 15;
    const int r = blockIdx.x * 16 + w * 4 + (lane >> 4);

    const float4* s4 = (const float4*)(src + (size_t)r * 128 + jg * 8);
    float4 a = s4[0], b = s4[1];

    uint32_t w0 = __builtin_amdgcn_cvt_pk_fp8_f32(a.x, a.y, 0, false);
    w0 = __builtin_amdgcn_cvt_pk_fp8_f32(a.z, a.w, w0, true);
    uint32_t w1 = __builtin_amdgcn_cvt_pk_fp8_f32(b.x, b.y, 0, false);
    w1 = __builtin_amdgcn_cvt_pk_fp8_f32(b.z, b.w, w1, true);

    *(uint2*)(dst + (jg >> 3) * 524288 + ((jg >> 2) & 1) * 262144
                  + ((jg >> 1) & 1) * 131072 + r * 16 + (jg & 1) * 8)
        = make_uint2(w0, w1);

    float sq = a.x*a.x + a.y*a.y + a.z*a.z + a.w*a.w
             + b.x*b.x + b.y*b.y + b.z*b.z + b.w*b.w;
    sq += __shfl_xor(sq, 1); sq += __shfl_xor(sq, 2);
    sq += __shfl_xor(sq, 4); sq += __shfl_xor(sq, 8);
    if (jg == 0) nrm[r] = sq;
}

// dist: 256x128 tile per block, 512 threads = 8 waves in a 4x2 grid, each
// wave a 64x64 sub-tile with the r2-verified body (acc[2][2], no tile
// loops). LDS ~50.7KB -> 3 blocks/CU = 24 waves/CU (r2: 16), 2048 blocks
// (r2: 4096) -> convoy/latency amortized. Grid (32,64), bx = 256-row
// A group, by = 128-row B group.
__global__ __launch_bounds__(512, 6) void dist_kernel(const uint8_t* __restrict__ Ak,
                                                      const uint8_t* __restrict__ Bk,
                                                      const float* __restrict__ xxg,
                                                      const float* __restrict__ yyg,
                                                      float* __restrict__ partials) {
    __shared__ uint8_t sA[32768] __attribute__((aligned(16)));
    __shared__ uint8_t sB[16384] __attribute__((aligned(16)));
    __shared__ float xxl[256];
    __shared__ float yyl[128];
    __shared__ float wsum[8];

    const int tid = threadIdx.x;
    const int lane = tid & 63;
    const int wid = tid >> 6;
    const int wr = wid >> 1, wc = wid & 1;      // 4x2 wave grid, each 64x64
    const int bx = blockIdx.x, by = blockIdx.y;

    // Stage A (32KB = 32 chunks of 1KB) + B (16KB = 16 chunks); 48 chunks,
    // 6 per wave. A chunk c<32: s = c>>2, rowblock rb = c&3 (256 rows).
    // B chunk c>=32: cc = c-32, s = cc>>1, half = cc&1 (128 rows).
    {
        const int c0 = wid * 6;
        #pragma unroll
        for (int i = 0; i < 6; ++i) {
            int c = c0 + i;
            const uint8_t* g;
            uint8_t* l;
            if (c < 32) {
                int s = c >> 2, rb = c & 3;
                g = Ak + (s >> 2) * 524288 + ((s >> 1) & 1) * 262144
                       + (s & 1) * 131072
                       + (size_t)(bx * 256 + rb * 64 + lane) * 16;
                l = sA + s * 4096 + rb * 1024 + lane * 16;
            } else {
                int cc = c - 32, s = cc >> 1, half = cc & 1;
                g = Bk + (s >> 2) * 524288 + ((s >> 1) & 1) * 262144
                       + (s & 1) * 131072
                       + (size_t)(by * 128 + half * 64 + lane) * 16;
                l = sB + s * 2048 + half * 1024 + lane * 16;
            }
            __builtin_amdgcn_global_load_lds(
                (const __attribute__((address_space(1))) unsigned int*)g,
                (__attribute__((address_space(3))) unsigned int*)l, 16, 0, 0);
        }
    }
    if (tid < 256)      xxl[tid] = xxg[bx * 256 + tid];
    else if (tid < 384) yyl[tid - 256] = yyg[by * 128 + (tid - 256)];
    __syncthreads();

    const int lm = lane & 31;
    const int fh = lane >> 5;                   // k-half within a 64-k step
    const v4i* A4 = (const v4i*)sA;             // [s][row] 16B units, 256 rows/seg
    const v4i* B4 = (const v4i*)sB;             // [s][row] 16B units, 128 rows/seg

    f32x16 acc[2][2] = {};
    #pragma unroll
    for (int S = 0; S < 2; ++S) {               // two K=64 steps
        const int sb = S * 4 + fh * 2;          // segment base (q=0)
        v4i a0l = A4[(sb + 0) * 256 + wr * 64 + lm];
        v4i a0h = A4[(sb + 1) * 256 + wr * 64 + lm];
        v4i a1l = A4[(sb + 0) * 256 + wr * 64 + 32 + lm];
        v4i a1h = A4[(sb + 1) * 256 + wr * 64 + 32 + lm];
        v4i b0l = B4[(sb + 0) * 128 + wc * 64 + lm];
        v4i b0h = B4[(sb + 1) * 128 + wc * 64 + lm];
        v4i b1l = B4[(sb + 0) * 128 + wc * 64 + 32 + lm];
        v4i b1h = B4[(sb + 1) * 128 + wc * 64 + 32 + lm];
        v8i a0 = __builtin_shufflevector(a0l, a0h, 0, 1, 2, 3, 4, 5, 6, 7);
        v8i a1 = __builtin_shufflevector(a1l, a1h, 0, 1, 2, 3, 4, 5, 6, 7);
        v8i b0 = __builtin_shufflevector(b0l, b0h, 0, 1, 2, 3, 4, 5, 6, 7);
        v8i b1 = __builtin_shufflevector(b1l, b1h, 0, 1, 2, 3, 4, 5, 6, 7);
        acc[0][0] = __builtin_amdgcn_mfma_scale_f32_32x32x64_f8f6f4(
                        a0, b0, acc[0][0], 0, 0, 0, 0x7F7F7F7F, 0, 0x7F7F7F7F);
        acc[0][1] = __builtin_amdgcn_mfma_scale_f32_32x32x64_f8f6f4(
                        a0, b1, acc[0][1], 0, 0, 0, 0x7F7F7F7F, 0, 0x7F7F7F7F);
        acc[1][0] = __builtin_amdgcn_mfma_scale_f32_32x32x64_f8f6f4(
                        a1, b0, acc[1][0], 0, 0, 0, 0x7F7F7F7F, 0, 0x7F7F7F7F);
        acc[1][1] = __builtin_amdgcn_mfma_scale_f32_32x32x64_f8f6f4(
                        a1, b1, acc[1][1], 0, 0, 0, 0x7F7F7F7F, 0, 0x7F7F7F7F);
    }

    // Epilogue: s += sqrt(|xx+yy-2c|); abs is a free v_sqrt input mod.
    float s0 = 0.0f, s1 = 0.0f;
    #pragma unroll
    for (int tr = 0; tr < 2; ++tr) {
        // ml = wr*64 + tr*32 + 8*(r>>2) + 4*fh + (r&3): 4 aligned float4 runs.
        float xv[16];
        #pragma unroll
        for (int q = 0; q < 4; ++q) {
            float4 t = *(const float4*)&xxl[wr * 64 + tr * 32 + 8 * q + 4 * fh];
            xv[q * 4 + 0] = t.x; xv[q * 4 + 1] = t.y;
            xv[q * 4 + 2] = t.z; xv[q * 4 + 3] = t.w;
        }
        #pragma unroll
        for (int tc = 0; tc < 2; ++tc) {
            float yv = yyl[wc * 64 + tc * 32 + lm];
            #pragma unroll
            for (int r = 0; r < 16; ++r) {
                float d2 = fmaf(-2.0f, acc[tr][tc][r], xv[r] + yv);
                float d = __builtin_amdgcn_sqrtf(__builtin_fabsf(d2));
                if (r & 1) s1 += d; else s0 += d;
            }
        }
    }
    float s = s0 + s1;

    // Diagonal correction: wave's global row-base == col-base.
    if (bx * 4 + wr == by * 2 + wc) {
        #pragma unroll
        for (int t = 0; t < 2; ++t) {
            #pragma unroll
            for (int r = 0; r < 16; ++r) {
                int row = (r & 3) + 8 * (r >> 2) + 4 * fh;
                if (row == lm) {
                    float xvv = xxl[wr * 64 + t * 32 + row];
                    float yvv = yyl[wc * 64 + t * 32 + row];
                    float d2 = fmaf(-2.0f, acc[t][t][r], xvv + yvv);
                    s -= 2.0f * __builtin_amdgcn_sqrtf(__builtin_fabsf(d2));
                }
            }
        }
    }

    #pragma unroll
    for (int off = 32; off > 0; off >>= 1) s += __shfl_down(s, off);
    if (lane == 0) wsum[wid] = s;
    __syncthreads();
    if (tid == 0) {
        float bs = ((wsum[0] + wsum[1]) + (wsum[2] + wsum[3]))
                 + ((wsum[4] + wsum[5]) + (wsum[6] + wsum[7]));
        partials[by * 32 + bx] = bs;
    }
}

__global__ __launch_bounds__(256) void reduce_kernel(const float* __restrict__ partials,
                                                     float* __restrict__ out) {
    __shared__ float wsum[4];
    float s = 0.0f;
    #pragma unroll
    for (int i = 0; i < 8; ++i) s += partials[threadIdx.x + i * 256];
    #pragma unroll
    for (int off = 32; off > 0; off >>= 1) s += __shfl_down(s, off);
    int lane = threadIdx.x & 63, wid = threadIdx.x >> 6;
    if (lane == 0) wsum[wid] = s;
    __syncthreads();
    if (threadIdx.x == 0)
        out[0] = (wsum[0] + wsum[1] + wsum[2] + wsum[3]) * (0.1f / 8192.0f);
}

extern "C" void kernel_launch(void* const* d_in, const int* in_sizes, int n_in,
                              void* d_out, int out_size, void* d_ws, size_t ws_size,
                              hipStream_t stream) {
    const float* output = (const float*)d_in[0];
    const float* target = (const float*)d_in[1];

    uint8_t* ws = (uint8_t*)d_ws;
    uint8_t* ak      = ws;                                      // A fp8 (1MB) + B fp8 (1MB)
    float*   xxyy    = (float*)(ws + (2u << 20));               // xx (32KB) + yy (32KB)
    float*   partial = (float*)(ws + (2u << 20) + (64u << 10)); // 2048 f32

    prep_kernel<<<dim3(512, 2), 256, 0, stream>>>(output, target, ak, xxyy);
    dist_kernel<<<dim3(32, 64), 512, 0, stream>>>(ak, ak + (1u << 20),
                                                  xxyy, xxyy + BDIM, partial);
    reduce_kernel<<<1, 256, 0, stream>>>(partial, (float*)d_out);
}

// Round 8
// 79.696 us; speedup vs baseline: 1.7626x; 1.7626x over previous
//
#include <hip/hip_runtime.h>
#include <stdint.h>

typedef float f32x16 __attribute__((ext_vector_type(16)));
typedef int v8i __attribute__((ext_vector_type(8)));
typedef int v4i __attribute__((ext_vector_type(4)));

#define BDIM 8192

// fp8 matrices stored 16B-run k-major for the K=64 scaled MFMA:
//   for byte (row, k): S = k>>6 (MFMA step), h = (k>>5)&1 (lane k-half),
//   q = (k>>4)&1 (16B half of the 32B run):
//   addr = S*524288 + h*262144 + q*131072 + row*16 + (k&15)     (1 MB per matrix)
// Segment index s = S*4 + h*2 + q (8 segments per matrix). v8i = (q0 16B,
// q1 16B) reproduces the 32B k-run byte order. Scales uniform 1.0 (0x7F).
//
// REGISTER KNIFE-EDGE (r3/r4/r7): per-wave body = 64 AGPR acc + ~56 VGPR
// = ~120 unified regs. Any cap below that spills the accumulators to
// scratch (r7: __launch_bounds__(512,6) -> 85-reg cap -> 238 MB spill
// writes). Occupancy is therefore hard-capped at 4 waves/SIMD; scale
// via block SHAPE (more waves/block), never via min-waves pressure and
// never via per-wave tile loops (r3/r4).
//
// GRID-RENDEZVOUS IS DEAD (r1/r6): release/acquire at agent scope = L2
// flush storm (+47us); even relaxed returning RMWs on one counter
// serialize 4096 blocks at the coherence point (+30us). 3-kernel form.

// fp32 [8192,128] -> fp8 e4m3 (16B-run layout) + fp32 row sum-of-squares.
__global__ __launch_bounds__(256) void prep_kernel(const float* __restrict__ out_f,
                                                   const float* __restrict__ tgt_f,
                                                   uint8_t* __restrict__ ak,
                                                   float* __restrict__ xxyy) {
    const float* src = blockIdx.y ? tgt_f : out_f;
    uint8_t* dst = ak + (size_t)blockIdx.y * (1u << 20);
    float* nrm = xxyy + (size_t)blockIdx.y * BDIM;

    const int tid = threadIdx.x;
    const int lane = tid & 63;
    const int w = tid >> 6;
    const int jg = lane & 15;
    const int r = blockIdx.x * 16 + w * 4 + (lane >> 4);

    const float4* s4 = (const float4*)(src + (size_t)r * 128 + jg * 8);
    float4 a = s4[0], b = s4[1];

    uint32_t w0 = __builtin_amdgcn_cvt_pk_fp8_f32(a.x, a.y, 0, false);
    w0 = __builtin_amdgcn_cvt_pk_fp8_f32(a.z, a.w, w0, true);
    uint32_t w1 = __builtin_amdgcn_cvt_pk_fp8_f32(b.x, b.y, 0, false);
    w1 = __builtin_amdgcn_cvt_pk_fp8_f32(b.z, b.w, w1, true);

    *(uint2*)(dst + (jg >> 3) * 524288 + ((jg >> 2) & 1) * 262144
                  + ((jg >> 1) & 1) * 131072 + r * 16 + (jg & 1) * 8)
        = make_uint2(w0, w1);

    float sq = a.x*a.x + a.y*a.y + a.z*a.z + a.w*a.w
             + b.x*b.x + b.y*b.y + b.z*b.z + b.w*b.w;
    sq += __shfl_xor(sq, 1); sq += __shfl_xor(sq, 2);
    sq += __shfl_xor(sq, 4); sq += __shfl_xor(sq, 8);
    if (jg == 0) nrm[r] = sq;
}

// dist: 256x128 tile per block, 512 threads = 8 waves in a 4x2 grid, each
// wave a 64x64 sub-tile with the r2-verified body (acc[2][2], no tile
// loops). __launch_bounds__(512,2): 256-reg cap (no spill; r7's (512,6)
// capped at 85 and spilled acc). 2 blocks/CU reg-limited = 16 waves/CU
// (same as r2) but 2048 blocks instead of 4096 -> half the block
// prologue/tail slots, A staged once per 256 rows.
__global__ __launch_bounds__(512, 2) void dist_kernel(const uint8_t* __restrict__ Ak,
                                                      const uint8_t* __restrict__ Bk,
                                                      const float* __restrict__ xxg,
                                                      const float* __restrict__ yyg,
                                                      float* __restrict__ partials) {
    __shared__ uint8_t sA[32768] __attribute__((aligned(16)));
    __shared__ uint8_t sB[16384] __attribute__((aligned(16)));
    __shared__ float xxl[256];
    __shared__ float yyl[128];
    __shared__ float wsum[8];

    const int tid = threadIdx.x;
    const int lane = tid & 63;
    const int wid = tid >> 6;
    const int wr = wid >> 1, wc = wid & 1;      // 4x2 wave grid, each 64x64
    const int bx = blockIdx.x, by = blockIdx.y;

    // Stage A (32KB = 32 chunks of 1KB) + B (16KB = 16 chunks); 48 chunks,
    // 6 per wave. A chunk c<32: s = c>>2, rowblock rb = c&3 (256 rows).
    // B chunk c>=32: cc = c-32, s = cc>>1, half = cc&1 (128 rows).
    {
        const int c0 = wid * 6;
        #pragma unroll
        for (int i = 0; i < 6; ++i) {
            int c = c0 + i;
            const uint8_t* g;
            uint8_t* l;
            if (c < 32) {
                int s = c >> 2, rb = c & 3;
                g = Ak + (s >> 2) * 524288 + ((s >> 1) & 1) * 262144
                       + (s & 1) * 131072
                       + (size_t)(bx * 256 + rb * 64 + lane) * 16;
                l = sA + s * 4096 + rb * 1024 + lane * 16;
            } else {
                int cc = c - 32, s = cc >> 1, half = cc & 1;
                g = Bk + (s >> 2) * 524288 + ((s >> 1) & 1) * 262144
                       + (s & 1) * 131072
                       + (size_t)(by * 128 + half * 64 + lane) * 16;
                l = sB + s * 2048 + half * 1024 + lane * 16;
            }
            __builtin_amdgcn_global_load_lds(
                (const __attribute__((address_space(1))) unsigned int*)g,
                (__attribute__((address_space(3))) unsigned int*)l, 16, 0, 0);
        }
    }
    if (tid < 256)      xxl[tid] = xxg[bx * 256 + tid];
    else if (tid < 384) yyl[tid - 256] = yyg[by * 128 + (tid - 256)];
    __syncthreads();

    const int lm = lane & 31;
    const int fh = lane >> 5;                   // k-half within a 64-k step
    const v4i* A4 = (const v4i*)sA;             // [s][row] 16B units, 256 rows/seg
    const v4i* B4 = (const v4i*)sB;             // [s][row] 16B units, 128 rows/seg

    f32x16 acc[2][2] = {};
    #pragma unroll
    for (int S = 0; S < 2; ++S) {               // two K=64 steps
        const int sb = S * 4 + fh * 2;          // segment base (q=0)
        v4i a0l = A4[(sb + 0) * 256 + wr * 64 + lm];
        v4i a0h = A4[(sb + 1) * 256 + wr * 64 + lm];
        v4i a1l = A4[(sb + 0) * 256 + wr * 64 + 32 + lm];
        v4i a1h = A4[(sb + 1) * 256 + wr * 64 + 32 + lm];
        v4i b0l = B4[(sb + 0) * 128 + wc * 64 + lm];
        v4i b0h = B4[(sb + 1) * 128 + wc * 64 + lm];
        v4i b1l = B4[(sb + 0) * 128 + wc * 64 + 32 + lm];
        v4i b1h = B4[(sb + 1) * 128 + wc * 64 + 32 + lm];
        v8i a0 = __builtin_shufflevector(a0l, a0h, 0, 1, 2, 3, 4, 5, 6, 7);
        v8i a1 = __builtin_shufflevector(a1l, a1h, 0, 1, 2, 3, 4, 5, 6, 7);
        v8i b0 = __builtin_shufflevector(b0l, b0h, 0, 1, 2, 3, 4, 5, 6, 7);
        v8i b1 = __builtin_shufflevector(b1l, b1h, 0, 1, 2, 3, 4, 5, 6, 7);
        acc[0][0] = __builtin_amdgcn_mfma_scale_f32_32x32x64_f8f6f4(
                        a0, b0, acc[0][0], 0, 0, 0, 0x7F7F7F7F, 0, 0x7F7F7F7F);
        acc[0][1] = __builtin_amdgcn_mfma_scale_f32_32x32x64_f8f6f4(
                        a0, b1, acc[0][1], 0, 0, 0, 0x7F7F7F7F, 0, 0x7F7F7F7F);
        acc[1][0] = __builtin_amdgcn_mfma_scale_f32_32x32x64_f8f6f4(
                        a1, b0, acc[1][0], 0, 0, 0, 0x7F7F7F7F, 0, 0x7F7F7F7F);
        acc[1][1] = __builtin_amdgcn_mfma_scale_f32_32x32x64_f8f6f4(
                        a1, b1, acc[1][1], 0, 0, 0, 0x7F7F7F7F, 0, 0x7F7F7F7F);
    }

    // Epilogue: s += sqrt(|xx+yy-2c|); abs is a free v_sqrt input mod.
    float s0 = 0.0f, s1 = 0.0f;
    #pragma unroll
    for (int tr = 0; tr < 2; ++tr) {
        // ml = wr*64 + tr*32 + 8*(r>>2) + 4*fh + (r&3): 4 aligned float4 runs.
        float xv[16];
        #pragma unroll
        for (int q = 0; q < 4; ++q) {
            float4 t = *(const float4*)&xxl[wr * 64 + tr * 32 + 8 * q + 4 * fh];
            xv[q * 4 + 0] = t.x; xv[q * 4 + 1] = t.y;
            xv[q * 4 + 2] = t.z; xv[q * 4 + 3] = t.w;
        }
        #pragma unroll
        for (int tc = 0; tc < 2; ++tc) {
            float yv = yyl[wc * 64 + tc * 32 + lm];
            #pragma unroll
            for (int r = 0; r < 16; ++r) {
                float d2 = fmaf(-2.0f, acc[tr][tc][r], xv[r] + yv);
                float d = __builtin_amdgcn_sqrtf(__builtin_fabsf(d2));
                if (r & 1) s1 += d; else s0 += d;
            }
        }
    }
    float s = s0 + s1;

    // Diagonal correction: wave's global row-base == col-base.
    if (bx * 4 + wr == by * 2 + wc) {
        #pragma unroll
        for (int t = 0; t < 2; ++t) {
            #pragma unroll
            for (int r = 0; r < 16; ++r) {
                int row = (r & 3) + 8 * (r >> 2) + 4 * fh;
                if (row == lm) {
                    float xvv = xxl[wr * 64 + t * 32 + row];
                    float yvv = yyl[wc * 64 + t * 32 + row];
                    float d2 = fmaf(-2.0f, acc[t][t][r], xvv + yvv);
                    s -= 2.0f * __builtin_amdgcn_sqrtf(__builtin_fabsf(d2));
                }
            }
        }
    }

    #pragma unroll
    for (int off = 32; off > 0; off >>= 1) s += __shfl_down(s, off);
    if (lane == 0) wsum[wid] = s;
    __syncthreads();
    if (tid == 0) {
        float bs = ((wsum[0] + wsum[1]) + (wsum[2] + wsum[3]))
                 + ((wsum[4] + wsum[5]) + (wsum[6] + wsum[7]));
        partials[by * 32 + bx] = bs;
    }
}

__global__ __launch_bounds__(256) void reduce_kernel(const float* __restrict__ partials,
                                                     float* __restrict__ out) {
    __shared__ float wsum[4];
    float s = 0.0f;
    #pragma unroll
    for (int i = 0; i < 8; ++i) s += partials[threadIdx.x + i * 256];
    #pragma unroll
    for (int off = 32; off > 0; off >>= 1) s += __shfl_down(s, off);
    int lane = threadIdx.x & 63, wid = threadIdx.x >> 6;
    if (lane == 0) wsum[wid] = s;
    __syncthreads();
    if (threadIdx.x == 0)
        out[0] = (wsum[0] + wsum[1] + wsum[2] + wsum[3]) * (0.1f / 8192.0f);
}

extern "C" void kernel_launch(void* const* d_in, const int* in_sizes, int n_in,
                              void* d_out, int out_size, void* d_ws, size_t ws_size,
                              hipStream_t stream) {
    const float* output = (const float*)d_in[0];
    const float* target = (const float*)d_in[1];

    uint8_t* ws = (uint8_t*)d_ws;
    uint8_t* ak      = ws;                                      // A fp8 (1MB) + B fp8 (1MB)
    float*   xxyy    = (float*)(ws + (2u << 20));               // xx (32KB) + yy (32KB)
    float*   partial = (float*)(ws + (2u << 20) + (64u << 10)); // 2048 f32

    prep_kernel<<<dim3(512, 2), 256, 0, stream>>>(output, target, ak, xxyy);
    dist_kernel<<<dim3(32, 64), 512, 0, stream>>>(ak, ak + (1u << 20),
                                                  xxyy, xxyy + BDIM, partial);
    reduce_kernel<<<1, 256, 0, stream>>>(partial, (float*)d_out);
}